// Round 3
// baseline (4707.791 us; speedup 1.0000x reference)
//
#include <hip/hip_runtime.h>
#include <hip/hip_bf16.h>
#include <stdint.h>

#define N_ 256
#define T_ 128
#define D_ 1024
#define H_ 1024
#define FH_ 4096
#define K2_ 2048

typedef __bf16 bf16x8 __attribute__((ext_vector_type(8)));
typedef float f32x4 __attribute__((ext_vector_type(4)));

// ---------------- transpose + cast fp32 -> bf16 ----------------
// dst[c][dst_coloff + r] = (bf16) src[r][c]
__global__ __launch_bounds__(256) void transpose_cast(
    const float* __restrict__ src, int cols,
    __hip_bfloat16* __restrict__ dst, int dst_stride, int dst_coloff)
{
    __shared__ float tile[32][33];
    int cb = blockIdx.x * 32, rb = blockIdx.y * 32;
    int tx = threadIdx.x, ty = threadIdx.y;  // (32, 8)
#pragma unroll
    for (int i = 0; i < 4; i++)
        tile[ty + i * 8][tx] = src[(size_t)(rb + ty + i * 8) * cols + cb + tx];
    __syncthreads();
#pragma unroll
    for (int i = 0; i < 4; i++)
        dst[(size_t)(cb + ty + i * 8) * dst_stride + dst_coloff + rb + tx] =
            __float2bfloat16(tile[tx][ty + i * 8]);
}

// ---------------- xproj GEMM: C[g][j] = sum_k x[g][k] * WxT[j][k] ----------
#define BM 64
#define BN 128
#define BK 64
#define BKP 72

__global__ __launch_bounds__(256) void gemm_x(
    const float* __restrict__ Xf,
    const __hip_bfloat16* __restrict__ BT,
    float* __restrict__ C, int t0)
{
    __shared__ __hip_bfloat16 Al[BM][BKP];
    __shared__ __hip_bfloat16 Bl[BN][BKP];
    const int tid = threadIdx.x;
    const int lane = tid & 63, wid = tid >> 6;
    const int m0 = blockIdx.y * BM, n0 = blockIdx.x * BN;
    const int wm = (wid >> 1) * 32, wn = (wid & 1) * 64;
    const int rs = tid >> 3, kc = (tid & 7) * 8;
    f32x4 acc[2][4] = {};

    for (int k0 = 0; k0 < D_; k0 += BK) {
#pragma unroll
        for (int p = 0; p < BM; p += 32) {
            int r = rs + p;
            int g = m0 + r;
            int nn = g & 255, tl = g >> 8;
            const float* s = Xf + ((size_t)nn * T_ + (t0 + tl)) * D_ + k0 + kc;
            float4 v0 = *reinterpret_cast<const float4*>(s);
            float4 v1 = *reinterpret_cast<const float4*>(s + 4);
            __hip_bfloat16 h8[8];
            h8[0] = __float2bfloat16(v0.x); h8[1] = __float2bfloat16(v0.y);
            h8[2] = __float2bfloat16(v0.z); h8[3] = __float2bfloat16(v0.w);
            h8[4] = __float2bfloat16(v1.x); h8[5] = __float2bfloat16(v1.y);
            h8[6] = __float2bfloat16(v1.z); h8[7] = __float2bfloat16(v1.w);
            *reinterpret_cast<int4*>(&Al[r][kc]) = *reinterpret_cast<const int4*>(h8);
        }
#pragma unroll
        for (int p = 0; p < BN; p += 32) {
            int r = rs + p;
            const __hip_bfloat16* s = BT + (size_t)(n0 + r) * D_ + k0 + kc;
            *reinterpret_cast<int4*>(&Bl[r][kc]) = *reinterpret_cast<const int4*>(s);
        }
        __syncthreads();
        const int ko = (lane >> 4) * 8;
#pragma unroll
        for (int kk = 0; kk < BK; kk += 32) {
            bf16x8 a0 = *reinterpret_cast<const bf16x8*>(&Al[wm + (lane & 15)][kk + ko]);
            bf16x8 a1 = *reinterpret_cast<const bf16x8*>(&Al[wm + 16 + (lane & 15)][kk + ko]);
#pragma unroll
            for (int ni = 0; ni < 4; ni++) {
                bf16x8 bq = *reinterpret_cast<const bf16x8*>(&Bl[wn + ni * 16 + (lane & 15)][kk + ko]);
                acc[0][ni] = __builtin_amdgcn_mfma_f32_16x16x32_bf16(a0, bq, acc[0][ni], 0, 0, 0);
                acc[1][ni] = __builtin_amdgcn_mfma_f32_16x16x32_bf16(a1, bq, acc[1][ni], 0, 0, 0);
            }
        }
        __syncthreads();
    }
    const int cr = (lane >> 4) * 4, ccol = lane & 15;
#pragma unroll
    for (int mi = 0; mi < 2; mi++)
#pragma unroll
        for (int ni = 0; ni < 4; ni++)
#pragma unroll
            for (int r = 0; r < 4; r++)
                C[(size_t)(m0 + wm + mi * 16 + cr + r) * FH_ + (n0 + wn + ni * 16 + ccol)] =
                    acc[mi][ni][r];
}

// ---------------- init: h0, c0, w0, attn0 (one n per WG) ----------------
__global__ __launch_bounds__(256) void init_full(
    const float* __restrict__ A, float* __restrict__ cbuf,
    __hip_bfloat16* __restrict__ hb)
{
    __shared__ float red[4][16];
    __shared__ float wl[16];
    const int n = blockIdx.x, tid = threadIdx.x;
    const int lane = tid & 63, wv = tid >> 6;
    const int h0i = tid * 4;
    float a[4][16];
    float hv[4];
#pragma unroll
    for (int q = 0; q < 4; q++) {
        const float4* Ap = reinterpret_cast<const float4*>(A + ((size_t)n * H_ + h0i + q) * 16);
        float4 q0 = Ap[0], q1 = Ap[1], q2 = Ap[2], q3 = Ap[3];
        a[q][0] = q0.x; a[q][1] = q0.y; a[q][2] = q0.z; a[q][3] = q0.w;
        a[q][4] = q1.x; a[q][5] = q1.y; a[q][6] = q1.z; a[q][7] = q1.w;
        a[q][8] = q2.x; a[q][9] = q2.y; a[q][10] = q2.z; a[q][11] = q2.w;
        a[q][12] = q3.x; a[q][13] = q3.y; a[q][14] = q3.z; a[q][15] = q3.w;
        float s = 0.f;
#pragma unroll
        for (int l = 0; l < 16; l++) s += a[q][l];
        hv[q] = s * 0.0625f;
    }
    *reinterpret_cast<float4*>(cbuf + (size_t)n * H_ + h0i) = *reinterpret_cast<float4*>(hv);
    {
        __hip_bfloat16 h4[4];
#pragma unroll
        for (int q = 0; q < 4; q++) h4[q] = __float2bfloat16(hv[q]);
        *reinterpret_cast<uint2*>(hb + (size_t)n * K2_ + h0i) = *reinterpret_cast<uint2*>(h4);
    }
    float sp[16];
#pragma unroll
    for (int l = 0; l < 16; l++) {
        sp[l] = hv[0] * a[0][l] + hv[1] * a[1][l] + hv[2] * a[2][l] + hv[3] * a[3][l];
#pragma unroll
        for (int off = 1; off < 64; off <<= 1) sp[l] += __shfl_xor(sp[l], off);
    }
    if (lane == 0) {
#pragma unroll
        for (int l = 0; l < 16; l++) red[wv][l] = sp[l];
    }
    __syncthreads();
    if (tid < 16) {
        float s = (red[0][tid] + red[1][tid] + red[2][tid] + red[3][tid]) * 0.03125f;
        float m = s;
        m = fmaxf(m, __shfl_xor(m, 8)); m = fmaxf(m, __shfl_xor(m, 4));
        m = fmaxf(m, __shfl_xor(m, 2)); m = fmaxf(m, __shfl_xor(m, 1));
        float e = __expf(s - m);
        float se = e;
        se += __shfl_xor(se, 8); se += __shfl_xor(se, 4);
        se += __shfl_xor(se, 2); se += __shfl_xor(se, 1);
        wl[tid] = e / se;
    }
    __syncthreads();
    float w[16];
#pragma unroll
    for (int l = 0; l < 16; l++) w[l] = wl[l];
    __hip_bfloat16 at4[4];
#pragma unroll
    for (int q = 0; q < 4; q++) {
        float s = 0.f;
#pragma unroll
        for (int l = 0; l < 16; l++) s += w[l] * a[q][l];
        at4[q] = __float2bfloat16(s);
    }
    *reinterpret_cast<uint2*>(hb + (size_t)n * K2_ + H_ + h0i) = *reinterpret_cast<uint2*>(at4);
}

// ---------------- wattn: reduce sp partials -> softmax -> attn -------------
// one n per WG; writes attn half of hb (current-parity buffer)
__global__ __launch_bounds__(256) void wattn(
    const float* __restrict__ sp_part, const float* __restrict__ A,
    __hip_bfloat16* __restrict__ hb)
{
    __shared__ float red[4][16];
    __shared__ float wl[16];
    const int n = blockIdx.x, tid = threadIdx.x;
    if (tid < 64) {
        const int g = tid >> 4, l = tid & 15;
        float s = 0.f;
        const float* sp = sp_part + ((size_t)n * 64 + g * 16) * 16 + l;
#pragma unroll
        for (int j = 0; j < 16; j++) s += sp[j * 16];
        red[g][l] = s;
    }
    __syncthreads();
    if (tid < 16) {
        float s = (red[0][tid] + red[1][tid] + red[2][tid] + red[3][tid]) * 0.03125f;
        float m = s;
        m = fmaxf(m, __shfl_xor(m, 8)); m = fmaxf(m, __shfl_xor(m, 4));
        m = fmaxf(m, __shfl_xor(m, 2)); m = fmaxf(m, __shfl_xor(m, 1));
        float e = __expf(s - m);
        float se = e;
        se += __shfl_xor(se, 8); se += __shfl_xor(se, 4);
        se += __shfl_xor(se, 2); se += __shfl_xor(se, 1);
        wl[tid] = e / se;
    }
    __syncthreads();
    float w[16];
#pragma unroll
    for (int l = 0; l < 16; l++) w[l] = wl[l];
    const int h0i = tid * 4;
    __hip_bfloat16 at4[4];
#pragma unroll
    for (int q = 0; q < 4; q++) {
        const float4* Ap = reinterpret_cast<const float4*>(A + ((size_t)n * H_ + h0i + q) * 16);
        float4 q0 = Ap[0], q1 = Ap[1], q2 = Ap[2], q3 = Ap[3];
        float s = w[0] * q0.x + w[1] * q0.y + w[2] * q0.z + w[3] * q0.w
                + w[4] * q1.x + w[5] * q1.y + w[6] * q1.z + w[7] * q1.w
                + w[8] * q2.x + w[9] * q2.y + w[10] * q2.z + w[11] * q2.w
                + w[12] * q3.x + w[13] * q3.y + w[14] * q3.z + w[15] * q3.w;
        at4[q] = __float2bfloat16(s);
    }
    *reinterpret_cast<uint2*>(hb + (size_t)n * K2_ + H_ + h0i) = *reinterpret_cast<uint2*>(at4);
}

// ---------------- fused GEMM(K=2048) + gates + sp-partials ----------------
// grid (jt=64, mt=4), block 256. WG: 64 n-rows x (16 hidden cols x 4 sections).
__global__ __launch_bounds__(256) void gemmgates(
    const __hip_bfloat16* __restrict__ hb_in,
    __hip_bfloat16* __restrict__ hb_out,
    const __hip_bfloat16* __restrict__ W2T,
    const float* __restrict__ xp,
    const float* __restrict__ bias,
    const float* __restrict__ Afp,
    float* __restrict__ cbuf,
    float* __restrict__ sp_part,
    float* __restrict__ out, int t)
{
    __shared__ __hip_bfloat16 Al[64][72];
    __shared__ __hip_bfloat16 Bl[64][72];
    __shared__ float pls[64][68];
    const int tid = threadIdx.x;
    const int lane = tid & 63, wv = tid >> 6;
    const int jt = blockIdx.x, mt = blockIdx.y;
    const int hc0 = jt * 16, n0 = mt * 64;
    const int rs = tid >> 3, kc = (tid & 7) * 8;
    const int wm = (wv >> 1) * 32, wn = (wv & 1) * 32;
    f32x4 acc[2][2] = {};

    for (int k0 = 0; k0 < K2_; k0 += 64) {
#pragma unroll
        for (int p = 0; p < 64; p += 32) {
            int r = rs + p;
            *reinterpret_cast<int4*>(&Al[r][kc]) =
                *reinterpret_cast<const int4*>(hb_in + (size_t)(n0 + r) * K2_ + k0 + kc);
            int grow = (r >> 4) * 1024 + hc0 + (r & 15);
            *reinterpret_cast<int4*>(&Bl[r][kc]) =
                *reinterpret_cast<const int4*>(W2T + (size_t)grow * K2_ + k0 + kc);
        }
        __syncthreads();
        const int ko = (lane >> 4) * 8;
#pragma unroll
        for (int kk = 0; kk < 64; kk += 32) {
            bf16x8 a0 = *reinterpret_cast<const bf16x8*>(&Al[wm + (lane & 15)][kk + ko]);
            bf16x8 a1 = *reinterpret_cast<const bf16x8*>(&Al[wm + 16 + (lane & 15)][kk + ko]);
            bf16x8 b0 = *reinterpret_cast<const bf16x8*>(&Bl[wn + (lane & 15)][kk + ko]);
            bf16x8 b1 = *reinterpret_cast<const bf16x8*>(&Bl[wn + 16 + (lane & 15)][kk + ko]);
            acc[0][0] = __builtin_amdgcn_mfma_f32_16x16x32_bf16(a0, b0, acc[0][0], 0, 0, 0);
            acc[0][1] = __builtin_amdgcn_mfma_f32_16x16x32_bf16(a0, b1, acc[0][1], 0, 0, 0);
            acc[1][0] = __builtin_amdgcn_mfma_f32_16x16x32_bf16(a1, b0, acc[1][0], 0, 0, 0);
            acc[1][1] = __builtin_amdgcn_mfma_f32_16x16x32_bf16(a1, b1, acc[1][1], 0, 0, 0);
        }
        __syncthreads();
    }
    {
        const int cr = (lane >> 4) * 4, cc = lane & 15;
#pragma unroll
        for (int mf = 0; mf < 2; mf++)
#pragma unroll
            for (int nf = 0; nf < 2; nf++)
#pragma unroll
                for (int r = 0; r < 4; r++)
                    pls[wm + mf * 16 + cr + r][wn + nf * 16 + cc] = acc[mf][nf][r];
    }
    __syncthreads();

    // epilogue: thread -> (n_l = tid>>2, 4 hidden cols hcq = (tid&3)*4)
    {
        const int n_l = tid >> 2, hcq = (tid & 3) * 4;
        const int nn = n0 + n_l;
        float pre_[4][4];
#pragma unroll
        for (int s = 0; s < 4; s++) {
            const int gj = s * 1024 + hc0 + hcq;
            float4 xv = *reinterpret_cast<const float4*>(xp + (size_t)nn * FH_ + gj);
            float4 bv = *reinterpret_cast<const float4*>(bias + gj);
            float4 pv = *reinterpret_cast<const float4*>(&pls[n_l][s * 16 + hcq]);
            pre_[s][0] = pv.x + xv.x + bv.x;
            pre_[s][1] = pv.y + xv.y + bv.y;
            pre_[s][2] = pv.z + xv.z + bv.z;
            pre_[s][3] = pv.w + xv.w + bv.w;
        }
        float cv[4];
        *reinterpret_cast<float4*>(cv) =
            *reinterpret_cast<const float4*>(cbuf + (size_t)nn * H_ + hc0 + hcq);
        float hq[4];
#pragma unroll
        for (int q = 0; q < 4; q++) {
            float iv = 1.f / (1.f + __expf(-pre_[0][q]));
            float fv = 1.f / (1.f + __expf(-pre_[1][q]));
            float ov = 1.f / (1.f + __expf(-pre_[2][q]));
            float gx = fminf(fmaxf(pre_[3][q], -20.f), 20.f);
            float eg = __expf(2.f * gx);
            float gv = (eg - 1.f) / (eg + 1.f);
            float cc2 = fv * cv[q] + iv * gv;
            cv[q] = cc2;
            float cx = fminf(fmaxf(cc2, -20.f), 20.f);
            float ec = __expf(2.f * cx);
            hq[q] = ov * (ec - 1.f) / (ec + 1.f);
        }
        *reinterpret_cast<float4*>(cbuf + (size_t)nn * H_ + hc0 + hcq) =
            *reinterpret_cast<float4*>(cv);
        *reinterpret_cast<float4*>(out + ((size_t)nn * T_ + t) * H_ + hc0 + hcq) =
            *reinterpret_cast<float4*>(hq);
        __hip_bfloat16 h4[4];
#pragma unroll
        for (int q = 0; q < 4; q++) h4[q] = __float2bfloat16(hq[q]);
        *reinterpret_cast<uint2*>(hb_out + (size_t)nn * K2_ + hc0 + hcq) =
            *reinterpret_cast<uint2*>(h4);

        // score partials over this WG's 16 hidden cols
        float spv[16];
#pragma unroll
        for (int l = 0; l < 16; l++) spv[l] = 0.f;
#pragma unroll
        for (int q = 0; q < 4; q++) {
            const float* ar = Afp + ((size_t)nn * H_ + hc0 + hcq + q) * 16;
            float4 a0 = *reinterpret_cast<const float4*>(ar);
            float4 a1 = *reinterpret_cast<const float4*>(ar + 4);
            float4 a2 = *reinterpret_cast<const float4*>(ar + 8);
            float4 a3 = *reinterpret_cast<const float4*>(ar + 12);
            spv[0] += hq[q] * a0.x; spv[1] += hq[q] * a0.y;
            spv[2] += hq[q] * a0.z; spv[3] += hq[q] * a0.w;
            spv[4] += hq[q] * a1.x; spv[5] += hq[q] * a1.y;
            spv[6] += hq[q] * a1.z; spv[7] += hq[q] * a1.w;
            spv[8] += hq[q] * a2.x; spv[9] += hq[q] * a2.y;
            spv[10] += hq[q] * a2.z; spv[11] += hq[q] * a2.w;
            spv[12] += hq[q] * a3.x; spv[13] += hq[q] * a3.y;
            spv[14] += hq[q] * a3.z; spv[15] += hq[q] * a3.w;
        }
#pragma unroll
        for (int l = 0; l < 16; l++) {
            spv[l] += __shfl_xor(spv[l], 1);
            spv[l] += __shfl_xor(spv[l], 2);
        }
        if ((tid & 3) == 0) {
            float* d = sp_part + ((size_t)nn * 64 + jt) * 16;
            *reinterpret_cast<float4*>(d)      = *reinterpret_cast<float4*>(&spv[0]);
            *reinterpret_cast<float4*>(d + 4)  = *reinterpret_cast<float4*>(&spv[4]);
            *reinterpret_cast<float4*>(d + 8)  = *reinterpret_cast<float4*>(&spv[8]);
            *reinterpret_cast<float4*>(d + 12) = *reinterpret_cast<float4*>(&spv[12]);
        }
    }
}

extern "C" void kernel_launch(void* const* d_in, const int* in_sizes, int n_in,
                              void* d_out, int out_size, void* d_ws, size_t ws_size,
                              hipStream_t stream)
{
    const float* x     = (const float*)d_in[0];
    const float* A     = (const float*)d_in[1];
    const float* Wx    = (const float*)d_in[2];
    const float* Wh    = (const float*)d_in[3];
    const float* Wattn = (const float*)d_in[4];
    const float* b     = (const float*)d_in[5];
    float* out = (float*)d_out;
    char* ws = (char*)d_ws;
    dim3 tb(32, 8);

    const size_t SZ_W2T = (size_t)FH_ * K2_ * 2;       // 16.8 MB
    const size_t SZ_WxT = (size_t)FH_ * D_ * 2;        // 8.4 MB
    const size_t SZ_HB  = (size_t)N_ * K2_ * 2;        // 1 MB (x2)
    const size_t SZ_C   = (size_t)N_ * H_ * 4;         // 1 MB
    const size_t SZ_SP  = (size_t)N_ * 64 * 16 * 4;    // 1 MB
    const size_t SZ_XPT = (size_t)N_ * FH_ * 4;        // 4.2 MB per t

    size_t off = 0;
    __hip_bfloat16* W2T = (__hip_bfloat16*)(ws + off); off += SZ_W2T;
    __hip_bfloat16* WxT = (__hip_bfloat16*)(ws + off); off += SZ_WxT;
    __hip_bfloat16* hb0 = (__hip_bfloat16*)(ws + off); off += SZ_HB;
    __hip_bfloat16* hb1 = (__hip_bfloat16*)(ws + off); off += SZ_HB;
    float* cbuf    = (float*)(ws + off); off += SZ_C;
    float* sp_part = (float*)(ws + off); off += SZ_SP;
    float* xproj   = (float*)(ws + off);

    size_t rem = (ws_size > off) ? (ws_size - off) : 0;
    int Tc = (int)(rem / SZ_XPT);
    if (Tc > 16) Tc = 16;
    if (Tc < 1) Tc = 1;

    // weight prep: W2T = [Wh; Wattn] transposed, WxT = Wx transposed
    transpose_cast<<<dim3(FH_ / 32, H_ / 32), tb, 0, stream>>>(Wh, FH_, W2T, K2_, 0);
    transpose_cast<<<dim3(FH_ / 32, H_ / 32), tb, 0, stream>>>(Wattn, FH_, W2T, K2_, H_);
    transpose_cast<<<dim3(FH_ / 32, D_ / 32), tb, 0, stream>>>(Wx, FH_, WxT, D_, 0);
    init_full<<<N_, 256, 0, stream>>>(A, cbuf, hb0);

    __hip_bfloat16* hbp[2] = {hb0, hb1};
    for (int t0 = 0; t0 < T_; t0 += Tc) {
        int tc = (T_ - t0 < Tc) ? (T_ - t0) : Tc;
        dim3 gx(FH_ / BN, tc * N_ / BM);
        gemm_x<<<gx, 256, 0, stream>>>(x, WxT, xproj, t0);
        for (int tl = 0; tl < tc; tl++) {
            int t = t0 + tl;
            if (t > 0)
                wattn<<<N_, 256, 0, stream>>>(sp_part, A, hbp[t & 1]);
            gemmgates<<<dim3(64, 4), 256, 0, stream>>>(
                hbp[t & 1], hbp[(t + 1) & 1], W2T,
                xproj + (size_t)tl * N_ * FH_, b, A, cbuf, sp_part, out, t);
        }
    }
}